// Round 21
// baseline (214.274 us; speedup 1.0000x reference)
//
#include <hip/hip_runtime.h>

#define N_NODE  40000
#define DIM     128
#define N_REL   8
#define N_EDGES 640000
#define PER_REL (N_EDGES / N_REL)
#define BS      128
#define SQ      50
#define NB      ((N_NODE + 255) / 256)   // 157 scan blocks
#define RSPLIT  8                         // relation split for proj kernel
#define RPB     (N_REL / RSPLIT)          // relations per block (=1)
#define CONVB   ((N_NODE * 64) / 256)     // 10000 conv blocks
#define HISTB   (N_EDGES / 1024)          // 625 hist blocks (4 edges/thread)

typedef unsigned int        u32;
typedef unsigned short      u16;
typedef unsigned char       u8;
typedef unsigned long long  u64;
typedef short  bf16x8 __attribute__((ext_vector_type(8)));
typedef float  f32x4  __attribute__((ext_vector_type(4)));
typedef float  f32x2  __attribute__((ext_vector_type(2)));
typedef u32    u32x4  __attribute__((ext_vector_type(4)));

#if __has_builtin(__builtin_amdgcn_cvt_pk_f32_fp8)
#define HW_FP8_DEC 1
#endif
#if __has_builtin(__builtin_amdgcn_cvt_pk_fp8_f32)
#define HW_FP8_ENC 1
#endif

__device__ __forceinline__ u16 f2bf(float f) {
  union { float f; u32 i; } c; c.f = f;
  u32 b = c.i;
  b += 0x7FFFu + ((b >> 16) & 1u);   // RNE
  return (u16)(b >> 16);
}
__device__ __forceinline__ float bf2f(u32 u) {
  union { u32 i; float f; } c; c.i = u << 16; return c.f;
}
__device__ __forceinline__ float bflo(u32 w) {
  union { u32 i; float f; } c; c.i = w << 16; return c.f;
}
__device__ __forceinline__ float bfhi(u32 w) {
  union { u32 i; float f; } c; c.i = w & 0xffff0000u; return c.f;
}
__device__ __forceinline__ u32 pk2(float a, float b) {
  return (u32)f2bf(a) | ((u32)f2bf(b) << 16);
}
// tanh via exp + hardware rcp (R11-proven)
__device__ __forceinline__ float tanh_fast(float x) {
  float e = __expf(2.f * x);
  return 1.f - 2.f * __builtin_amdgcn_rcpf(e + 1.f);
}

// ---- fp8 OCP e4m3fn software encode/decode (fallbacks; HW-guarded use) ----
__device__ __forceinline__ u32 f2fp8(float f) {
  union { float f; u32 i; } c; c.f = f;
  u32 b = c.i;
  u32 s = (b >> 24) & 0x80u;
  u32 mag = b & 0x7fffffffu;
  mag += 0x7FFFFu + ((mag >> 20) & 1u);      // RNE at bit 20
  int e8 = (int)(mag >> 23) - 120;
  if (e8 >= 16) return s | 0x7Eu;            // clamp to 448
  if (e8 <= 0) {                             // subnormal
    float af = fabsf(f) * 512.f + 0.5f;
    int m2 = (int)af;
    if (m2 > 7) return s | 0x08u;
    return s | (u32)m2;
  }
  return s | ((u32)e8 << 3) | ((mag >> 20) & 7u);
}
__device__ __forceinline__ float fp8d(u32 byte) {
  u32 em = byte & 0x7fu;
  u32 e  = em >> 3;
  u32 M  = e ? (em & 7u) + 8u : em;
  u32 E  = e ? e : 1u;
  union { u32 i; float f; } sc; sc.i = (E + 117u) << 23;   // 2^(E-10)
  float v = (float)M * sc.f;
  return (byte & 0x80u) ? -v : v;
}
__device__ __forceinline__ float fp8dot4(u32 ta, u32 ha) {
#ifdef HW_FP8_DEC
  f32x2 t0 = __builtin_amdgcn_cvt_pk_f32_fp8(ta, 0);
  f32x2 t1 = __builtin_amdgcn_cvt_pk_f32_fp8(ta, 1);
  f32x2 h0 = __builtin_amdgcn_cvt_pk_f32_fp8(ha, 0);
  f32x2 h1 = __builtin_amdgcn_cvt_pk_f32_fp8(ha, 1);
  return t0.x * h0.x + t0.y * h0.y + t1.x * h1.x + t1.y * h1.y;
#else
  return fp8d(ta & 255u) * fp8d(ha & 255u)
       + fp8d((ta >> 8) & 255u) * fp8d((ha >> 8) & 255u)
       + fp8d((ta >> 16) & 255u) * fp8d((ha >> 16) & 255u)
       + fp8d(ta >> 24) * fp8d(ha >> 24);
#endif
}
// decode 2 fp8 packed in low 16 bits of w
__device__ __forceinline__ f32x2 fp8pair(u32 w) {
#ifdef HW_FP8_DEC
  return __builtin_amdgcn_cvt_pk_f32_fp8(w, 0);
#else
  f32x2 r; r.x = fp8d(w & 255u); r.y = fp8d((w >> 8) & 255u); return r;
#endif
}
// encode 2 floats -> 2 fp8 bytes (low u16)
__device__ __forceinline__ u16 fp8enc2(float a, float b) {
#ifdef HW_FP8_ENC
  u32 pk = (u32)__builtin_amdgcn_cvt_pk_fp8_f32(a, b, 0, 0);
  return (u16)(pk & 0xffffu);
#else
  return (u16)(f2fp8(a) | (f2fp8(b) << 8));
#endif
}

// ==================================================================
// fused prep: conv_bf16 | hist+rank | wtrans | rsum8  (R17-proven)
// ==================================================================
__global__ void __launch_bounds__(256)
prep_kernel(const float* __restrict__ emb, u32* __restrict__ embb,
            const float* __restrict__ W, u16* __restrict__ Wtb,
            const float* __restrict__ rembw, float* __restrict__ rsum8,
            const int* __restrict__ hl, int* __restrict__ cnt,
            int* __restrict__ rank) {
  int bid = blockIdx.x;
  if (bid < CONVB) {
    int i = bid * 256 + threadIdx.x;
    float2 v = reinterpret_cast<const float2*>(emb)[i];
    embb[i] = pk2(v.x, v.y);
  } else if (bid < CONVB + HISTB) {
    int base = (bid - CONVB) * 1024 + threadIdx.x;
    int hn[4], rk[4];
    #pragma unroll
    for (int j = 0; j < 4; j++) hn[j] = hl[base + j * 256];
    #pragma unroll
    for (int j = 0; j < 4; j++) rk[j] = atomicAdd(&cnt[hn[j]], 1);
    #pragma unroll
    for (int j = 0; j < 4; j++) rank[base + j * 256] = rk[j];
  } else if (bid < CONVB + HISTB + N_REL) {
    int r = bid - CONVB - HISTB;
    const float* Wr = W + (size_t)r * DIM * DIM;
    u16* o = Wtb + (size_t)r * DIM * DIM;
    for (int x = threadIdx.x; x < DIM * DIM; x += 256) {
      int n = x >> 7, k = x & 127;
      o[x] = f2bf(Wr[k * DIM + n]);
    }
  } else {
    int wv = threadIdx.x >> 6, lane = threadIdx.x & 63;
    for (int r = wv; r < N_REL; r += 4) {
      float s = rembw[r * DIM + lane] + rembw[r * DIM + 64 + lane];
      #pragma unroll
      for (int o = 32; o; o >>= 1) s += __shfl_xor(s, o, 64);
      if (lane == 0) rsum8[r] = s;
    }
  }
}

// ==================================================================
// CSR scans (R17-proven)
// ==================================================================
__global__ void bsum_kernel(const int* __restrict__ cnt, int* __restrict__ bsum) {
  __shared__ int sd[256];
  int i = blockIdx.x * 256 + threadIdx.x;
  sd[threadIdx.x] = (i < N_NODE) ? cnt[i] : 0;
  __syncthreads();
  for (int o = 128; o; o >>= 1) {
    if (threadIdx.x < o) sd[threadIdx.x] += sd[threadIdx.x + o];
    __syncthreads();
  }
  if (!threadIdx.x) bsum[blockIdx.x] = sd[0];
}

__global__ void scan_bsum_kernel(int* __restrict__ bsum) {
  __shared__ int sd[256];
  int t = threadIdx.x;
  int orig = (t < NB) ? bsum[t] : 0;
  sd[t] = orig;
  __syncthreads();
  for (int o = 1; o < 256; o <<= 1) {
    int v = (t >= o) ? sd[t - o] : 0;
    __syncthreads();
    sd[t] += v;
    __syncthreads();
  }
  if (t < NB) bsum[t] = sd[t] - orig;
}

__global__ void scan_final_kernel(const int* __restrict__ cnt, const int* __restrict__ bsum,
                                  int* __restrict__ rowptr) {
  __shared__ int sd[256];
  int t = threadIdx.x;
  int i = blockIdx.x * 256 + t;
  int orig = (i < N_NODE) ? cnt[i] : 0;
  sd[t] = orig;
  __syncthreads();
  for (int o = 1; o < 256; o <<= 1) {
    int v = (t >= o) ? sd[t - o] : 0;
    __syncthreads();
    sd[t] += v;
    __syncthreads();
  }
  int ex = sd[t] - orig + bsum[blockIdx.x];
  if (i < N_NODE) {
    rowptr[i] = ex;
    if (i == N_NODE - 1) rowptr[N_NODE] = ex + orig;
  }
}

// scatter: atomic-free (R17-proven)
__global__ void __launch_bounds__(256)
scatter_kernel(const int* __restrict__ hl, const int* __restrict__ tl,
               const float* __restrict__ ain, const int* __restrict__ rowptr,
               const int* __restrict__ rank, u64* __restrict__ pay64) {
  int base = blockIdx.x * 1024 + threadIdx.x;
  int pos[4];
  u64 pl[4];
  #pragma unroll
  for (int j = 0; j < 4; j++) {
    int e = base + j * 256;
    int hn = hl[e];
    pos[j] = rowptr[hn] + rank[e];
    int r = e / PER_REL;
    u32 lo = (u32)tl[e] | ((u32)hn << 16);
    u32 hi = (u32)r | ((u32)f2bf(ain[e]) << 16);
    pl[j] = ((u64)hi << 32) | lo;
  }
  #pragma unroll
  for (int j = 0; j < 4; j++) pay64[pos[j]] = pl[j];
}

// ==================================================================
// hop0 spmm (R14-proven) + fp8 side-copy of ego1 for score pass
// ==================================================================
__global__ void __launch_bounds__(256)
spmm_pay0(const u32* __restrict__ xb, const u64* __restrict__ pay64,
          const int* __restrict__ rowptr, u32* __restrict__ outb,
          u16* __restrict__ outf8) {
  int row = (blockIdx.x * 256 + threadIdx.x) >> 6;
  if (row >= N_NODE) return;
  int lane = threadIdx.x & 63;
  int lo = rowptr[row], n = rowptr[row + 1] - lo;
  float ax = 0.f, ay = 0.f;
  const u32* xl = xb + lane;
  int p = 0;
  for (; p + 7 < n; p += 8) {
    u64 q[8]; u32 w[8];
    #pragma unroll
    for (int j = 0; j < 8; j++) q[j] = pay64[lo + p + j];
    #pragma unroll
    for (int j = 0; j < 8; j++) w[j] = xl[(size_t)((u32)q[j] & 0xffffu) << 6];
    #pragma unroll
    for (int j = 0; j < 8; j++) {
      float v = bf2f((u32)(q[j] >> 48));
      ax += v * bflo(w[j]);
      ay += v * bfhi(w[j]);
    }
  }
  for (; p < n; p++) {
    u64 q0 = pay64[lo + p];
    float v0 = bf2f((u32)(q0 >> 48));
    u32 w0 = xl[(size_t)((u32)q0 & 0xffffu) << 6];
    ax += v0 * bflo(w0);
    ay += v0 * bfhi(w0);
  }
  outb[((size_t)row << 6) + lane] = pk2(ax, ay);
  outf8[((size_t)row << 6) + lane] = fp8enc2(ax, ay);
}

// ==================================================================
// SINGLE-PASS score + aggregate + rowsum + normalize (hop 1).
// 8 lanes/edge, 8 edges/iter. Per edge: gather projf8 tanh-half (t) +
// raw-half (row, L1-hot) + xf8[t] (issued in same latency shadow).
// Lane accumulates e * x for its 16 dims; cross-group reduce at end.
// ==================================================================
__global__ void __launch_bounds__(256)
score_spmm(const u8* __restrict__ projf8, const u16* __restrict__ xf8,
           const u64* __restrict__ pay64, const int* __restrict__ rowptr,
           const float* __restrict__ rsum8, u32* __restrict__ outb) {
  int row = (blockIdx.x * 256 + threadIdx.x) >> 6;
  if (row >= N_NODE) return;
  int lane = threadIdx.x & 63;
  int g8 = lane >> 3, le8 = lane & 7;
  int lo = rowptr[row], n = rowptr[row + 1] - lo;
  const u8* xf8b = reinterpret_cast<const u8*>(xf8);

  float acc[16];
  #pragma unroll
  for (int i = 0; i < 16; i++) acc[i] = 0.f;
  float gsum = 0.f;

  for (int p0 = 0; p0 < n; p0 += 8) {
    int p = p0 + g8;
    bool valid = p < n;
    int r = 0;
    u32x4 xv = (u32x4){0u, 0u, 0u, 0u};
    float s = 0.f;
    if (valid) {
      u64 q = pay64[lo + p];
      int t = (int)((u32)q & 0xffffu);
      r = (int)((u32)(q >> 32) & 0xffu);
      const u8* base = projf8 + (size_t)r * N_NODE * 256;
      u32x4 tv = *reinterpret_cast<const u32x4*>(base + (size_t)t * 256 + le8 * 16);
      u32x4 hv = *reinterpret_cast<const u32x4*>(base + (size_t)row * 256 + 128 + le8 * 16);
      xv = *reinterpret_cast<const u32x4*>(xf8b + (size_t)t * 128 + le8 * 16);
      s = fp8dot4(tv[0], hv[0]) + fp8dot4(tv[1], hv[1])
        + fp8dot4(tv[2], hv[2]) + fp8dot4(tv[3], hv[3]);
    }
    #pragma unroll
    for (int o = 4; o; o >>= 1) s += __shfl_xor(s, o, 64);   // 8-lane group reduce
    if (valid) {
      float e = __expf(s + rsum8[r]);
      if (le8 == 0) gsum += e;
      #pragma unroll
      for (int c = 0; c < 4; c++) {
        f32x2 loP = fp8pair(xv[c]);
        f32x2 hiP = fp8pair(xv[c] >> 16);
        acc[c * 4 + 0] += e * loP.x;
        acc[c * 4 + 1] += e * loP.y;
        acc[c * 4 + 2] += e * hiP.x;
        acc[c * 4 + 3] += e * hiP.y;
      }
    }
  }

  // rowsum across wave (only le8==0 lanes carry nonzero)
  float rs = gsum;
  #pragma unroll
  for (int o = 32; o; o >>= 1) rs += __shfl_xor(rs, o, 64);
  float inv = (rs > 0.f) ? 1.f / rs : 0.f;

  // reduce acc across the 8 groups (lanes sharing le8)
  #pragma unroll
  for (int i = 0; i < 16; i++) {
    #pragma unroll
    for (int o = 8; o < 64; o <<= 1) acc[i] += __shfl_xor(acc[i], o, 64);
  }

  if (g8 == 0) {   // lanes 0..7 hold full sums for dims le8*16..+15
    u32 slot[8];
    #pragma unroll
    for (int j = 0; j < 8; j++) slot[j] = pk2(acc[2 * j] * inv, acc[2 * j + 1] * inv);
    u32* dst = outb + ((size_t)row << 6) + le8 * 8;
    *reinterpret_cast<u32x4*>(dst)     = (u32x4){slot[0], slot[1], slot[2], slot[3]};
    *reinterpret_cast<u32x4*>(dst + 4) = (u32x4){slot[4], slot[5], slot[6], slot[7]};
  }
}

// ==================================================================
// projection: A regs, B LDS, fp8 split-half epilogue (R18-proven)
// ==================================================================
__global__ void __launch_bounds__(256)
proj_mfma4(const u32* __restrict__ egob, const u16* __restrict__ Wtb,
           u8* __restrict__ projf8) {
  __shared__ u16 Buf[128 * 136];
  int tid = threadIdx.x;
  int rel0  = (blockIdx.x & (RSPLIT - 1)) * RPB;
  int gbase = (blockIdx.x / RSPLIT) * 128;

  for (int x = tid; x < 128 * 64; x += 256) {
    int m = x >> 6, d2 = x & 63;
    int gm = gbase + m; if (gm >= N_NODE) gm = N_NODE - 1;
    u32 v = egob[((size_t)gm << 6) + d2];
    int byte = (m * 256 + d2 * 4) ^ ((m & 7) << 4);
    *reinterpret_cast<u32*>(reinterpret_cast<char*>(Buf) + byte) = v;
  }
  __syncthreads();

  int w = tid >> 6, lane = tid & 63;
  int l15 = lane & 15, g = lane >> 4;

  bf16x8 afr[2][4];
  #pragma unroll
  for (int kk = 0; kk < 4; kk++) {
    int kb = (kk * 32 + g * 8) * 2;
    #pragma unroll
    for (int mt = 0; mt < 2; mt++) {
      int m = w * 32 + mt * 16 + l15;
      int byte = (m * 256 + kb) ^ ((m & 7) << 4);
      afr[mt][kk] = *reinterpret_cast<bf16x8*>(reinterpret_cast<char*>(Buf) + byte);
    }
  }
  __syncthreads();

  for (int rr = 0; rr < RPB; rr++) {
    int r = rel0 + rr;
    const u32* Wr32 = reinterpret_cast<const u32*>(Wtb + (size_t)r * DIM * DIM);
    for (int x = tid; x < 128 * 64; x += 256) {
      int n = x >> 6, k2 = x & 63;
      int byte = (n * 256 + k2 * 4) ^ ((n & 7) << 4);
      *reinterpret_cast<u32*>(reinterpret_cast<char*>(Buf) + byte) = Wr32[x];
    }
    __syncthreads();

    f32x4 acc[2][8];
    #pragma unroll
    for (int mt = 0; mt < 2; mt++)
      #pragma unroll
      for (int nt = 0; nt < 8; nt++) acc[mt][nt] = (f32x4){0.f, 0.f, 0.f, 0.f};

    #pragma unroll
    for (int kk = 0; kk < 4; kk++) {
      int kb = (kk * 32 + g * 8) * 2;
      #pragma unroll
      for (int nt = 0; nt < 8; nt++) {
        int n = nt * 16 + l15;
        int byte = (n * 256 + kb) ^ ((n & 7) << 4);
        bf16x8 b = *reinterpret_cast<bf16x8*>(reinterpret_cast<char*>(Buf) + byte);
        acc[0][nt] = __builtin_amdgcn_mfma_f32_16x16x32_bf16(afr[0][kk], b, acc[0][nt], 0, 0, 0);
        acc[1][nt] = __builtin_amdgcn_mfma_f32_16x16x32_bf16(afr[1][kk], b, acc[1][nt], 0, 0, 0);
      }
    }
    __syncthreads();

    char* BufB = reinterpret_cast<char*>(Buf);
    #pragma unroll
    for (int mt = 0; mt < 2; mt++)
      #pragma unroll
      for (int reg = 0; reg < 4; reg++) {
        int row = w * 32 + mt * 16 + g * 4 + reg;
        char* rb = BufB + row * 272;
        #pragma unroll
        for (int nt = 0; nt < 8; nt++) {
          float v = acc[mt][nt][reg];
          int col = nt * 16 + l15;
#ifdef HW_FP8_ENC
          u32 pk = (u32)__builtin_amdgcn_cvt_pk_fp8_f32(tanh_fast(v), v, 0, 0);
          rb[col]       = (char)(pk & 255u);
          rb[128 + col] = (char)((pk >> 8) & 255u);
#else
          rb[col]       = (char)f2fp8(tanh_fast(v));
          rb[128 + col] = (char)f2fp8(v);
#endif
        }
      }
    __syncthreads();

    const u32x4* Cs = reinterpret_cast<const u32x4*>(Buf);
    u32* dst = reinterpret_cast<u32*>(projf8 + (size_t)r * N_NODE * 256);
    for (int x = tid; x < 128 * 16; x += 256) {
      int row = x >> 4, q = x & 15;
      int node = gbase + row;
      if (node < N_NODE) {
        u32x4 v = Cs[row * 17 + q];
        *reinterpret_cast<u32x4*>(dst + ((size_t)node << 6) + q * 4) = v;
      }
    }
    __syncthreads();
  }
}

// ==================================================================
// local_agg via MFMA (R5-proven, unchanged)
// ==================================================================
__global__ void __launch_bounds__(512)
local_agg4(const float* __restrict__ emb, const u32* __restrict__ ego1b,
           const u32* __restrict__ ego2b, const int* __restrict__ inp,
           const int* __restrict__ Aadj,
           const float* __restrict__ a0, const float* __restrict__ a1,
           const float* __restrict__ a2, const float* __restrict__ a3,
           float* __restrict__ out_hidden, float* __restrict__ out_node,
           float* __restrict__ tmpK) {
  __shared__ u16   Qb[64 * 256];
  __shared__ u16   hTb[128 * 64];
  __shared__ float aC[4][256];
  __shared__ float S[4][64 * 66];
  __shared__ u16   P[64 * 64];
  __shared__ float sinv[64];
  __shared__ int   adjL[SQ * SQ];

  int b = blockIdx.x >> 1, which = blockIdx.x & 1;
  int tid = threadIdx.x;

  {
    int k = tid >> 7, d = tid & 127;
    const float* ap = (k == 0) ? a0 : (k == 1) ? a1 : (k == 2) ? a2 : a3;
    float av = ap[d];
    aC[k][d] = 0.6f * av;
    aC[k][128 + d] = 0.4f * av;
  }
  for (int x = tid; x < SQ * SQ; x += 512) adjL[x] = Aadj[b * SQ * SQ + x];
  for (int x = tid; x < 128 * 16; x += 512) {
    int d = x >> 4, j = 48 + (x & 15);
    if (j >= 50) {
      int byte = (d * 128 + j * 2) ^ ((d & 7) << 4);
      *reinterpret_cast<u16*>(reinterpret_cast<char*>(hTb) + byte) = 0;
    }
  }
  for (int x = tid; x < SQ * 64; x += 512) {
    int j = x >> 6, d2 = (x & 63) << 1;
    int node = inp[b * SQ + j];
    float v0, v1;
    if (which == 0) {
      float2 vv = *reinterpret_cast<const float2*>(emb + (size_t)node * DIM + d2);
      v0 = vv.x; v1 = vv.y;
      *reinterpret_cast<float2*>(out_node + (size_t)(b * SQ + j) * DIM + d2) = vv;
    } else {
      u32 w1 = ego1b[((size_t)node << 6) + (d2 >> 1)];
      u32 w2 = ego2b[((size_t)node << 6) + (d2 >> 1)];
      v0 = 0.5f * (bf2f(w1 & 0xffffu) + bf2f(w2 & 0xffffu));
      v1 = 0.5f * (bf2f(w1 >> 16) + bf2f(w2 >> 16));
    }
    u16 b0 = f2bf(v0), b1 = f2bf(v1);
    { int byte = (j * 512 + d2 * 2) ^ ((j & 7) << 4);
      *reinterpret_cast<u32*>(reinterpret_cast<char*>(Qb) + byte) = (u32)b0 | ((u32)b1 << 16); }
    { int byte = (j * 512 + 256 + d2 * 2) ^ ((j & 7) << 4);
      u32 m0 = b0 & 0x7fffu, m1 = b1 & 0x7fffu;
      *reinterpret_cast<u32*>(reinterpret_cast<char*>(Qb) + byte) = m0 | (m1 << 16); }
    { int byte = (d2 * 128 + j * 2) ^ ((d2 & 7) << 4);
      *reinterpret_cast<u16*>(reinterpret_cast<char*>(hTb) + byte) = b0; }
    { int byte = ((d2 + 1) * 128 + j * 2) ^ (((d2 + 1) & 7) << 4);
      *reinterpret_cast<u16*>(reinterpret_cast<char*>(hTb) + byte) = b1; }
  }
  __syncthreads();

  int w = tid >> 6, lane = tid & 63;
  int l15 = lane & 15, g = lane >> 4;

  {
    int k = w >> 1, half = w & 1;
    const float* aCk = aC[k];
    f32x4 acc[2][4];
    #pragma unroll
    for (int mt = 0; mt < 2; mt++)
      #pragma unroll
      for (int nt = 0; nt < 4; nt++) acc[mt][nt] = (f32x4){0.f, 0.f, 0.f, 0.f};
    for (int ks = 0; ks < 8; ks++) {
      int kb = ks * 32 + g * 8;
      float4 c01 = *reinterpret_cast<const float4*>(aCk + kb);
      float4 c23 = *reinterpret_cast<const float4*>(aCk + kb + 4);
      bf16x8 afr[2];
      #pragma unroll
      for (int mt = 0; mt < 2; mt++) {
        int m = (half * 2 + mt) * 16 + l15;
        int byte = (m * 512 + kb * 2) ^ ((m & 7) << 4);
        union { bf16x8 v; u32 u[4]; } qv, o;
        qv.v = *reinterpret_cast<bf16x8*>(reinterpret_cast<char*>(Qb) + byte);
        o.u[0] = pk2(bf2f(qv.u[0] & 0xffffu) * c01.x, bf2f(qv.u[0] >> 16) * c01.y);
        o.u[1] = pk2(bf2f(qv.u[1] & 0xffffu) * c01.z, bf2f(qv.u[1] >> 16) * c01.w);
        o.u[2] = pk2(bf2f(qv.u[2] & 0xffffu) * c23.x, bf2f(qv.u[2] >> 16) * c23.y);
        o.u[3] = pk2(bf2f(qv.u[3] & 0xffffu) * c23.z, bf2f(qv.u[3] >> 16) * c23.w);
        afr[mt] = o.v;
      }
      #pragma unroll
      for (int nt = 0; nt < 4; nt++) {
        int n = nt * 16 + l15;
        int byte = (n * 512 + kb * 2) ^ ((n & 7) << 4);
        bf16x8 bfr = *reinterpret_cast<bf16x8*>(reinterpret_cast<char*>(Qb) + byte);
        acc[0][nt] = __builtin_amdgcn_mfma_f32_16x16x32_bf16(afr[0], bfr, acc[0][nt], 0, 0, 0);
        acc[1][nt] = __builtin_amdgcn_mfma_f32_16x16x32_bf16(afr[1], bfr, acc[1][nt], 0, 0, 0);
      }
    }
    #pragma unroll
    for (int mt = 0; mt < 2; mt++)
      #pragma unroll
      for (int nt = 0; nt < 4; nt++)
        #pragma unroll
        for (int reg = 0; reg < 4; reg++) {
          int m = (half * 2 + mt) * 16 + g * 4 + reg;
          int n = nt * 16 + l15;
          S[k][m * 66 + n] = acc[mt][nt][reg];
        }
  }
  __syncthreads();

  for (int i = w; i < SQ; i += 8) {
    float p = 0.f;
    if (lane < SQ) {
      int sel = adjL[i * SQ + lane];
      if (sel > 0) p = __expf(S[sel - 1][i * 66 + lane]);
    }
    float s = p;
    #pragma unroll
    for (int off = 32; off; off >>= 1) s += __shfl_xor(s, off, 64);
    if (lane == 0) sinv[i] = (s > 0.f) ? 1.f / s : 0.f;
    int byte = (i * 128 + lane * 2) ^ ((i & 7) << 4);
    *reinterpret_cast<u16*>(reinterpret_cast<char*>(P) + byte) = f2bf(p);
  }
  __syncthreads();

  {
    int mt = w >> 1, ng = w & 1;
    f32x4 acc[4];
    #pragma unroll
    for (int nt = 0; nt < 4; nt++) acc[nt] = (f32x4){0.f, 0.f, 0.f, 0.f};
    #pragma unroll
    for (int ks = 0; ks < 2; ks++) {
      int kb = ks * 32 + g * 8;
      int m = mt * 16 + l15;
      int abyte = (m * 128 + kb * 2) ^ ((m & 7) << 4);
      bf16x8 afr = *reinterpret_cast<bf16x8*>(reinterpret_cast<char*>(P) + abyte);
      #pragma unroll
      for (int nt = 0; nt < 4; nt++) {
        int d = (ng * 4 + nt) * 16 + l15;
        int byte = (d * 128 + kb * 2) ^ ((d & 7) << 4);
        bf16x8 bfr = *reinterpret_cast<bf16x8*>(reinterpret_cast<char*>(hTb) + byte);
        acc[nt] = __builtin_amdgcn_mfma_f32_16x16x32_bf16(afr, bfr, acc[nt], 0, 0, 0);
      }
    }
    float* dst = which ? tmpK : out_hidden;
    #pragma unroll
    for (int nt = 0; nt < 4; nt++)
      #pragma unroll
      for (int reg = 0; reg < 4; reg++) {
        int i = mt * 16 + g * 4 + reg;
        if (i < SQ) {
          int d = (ng * 4 + nt) * 16 + l15;
          dst[(size_t)(b * SQ + i) * DIM + d] = acc[nt][reg] * sinv[i];
        }
      }
  }
}

__global__ void add_kernel(float* __restrict__ out, const float* __restrict__ add) {
  int i = blockIdx.x * 256 + threadIdx.x;
  float4 a = reinterpret_cast<const float4*>(add)[i];
  float4 o = reinterpret_cast<float4*>(out)[i];
  o.x += a.x; o.y += a.y; o.z += a.z; o.w += a.w;
  reinterpret_cast<float4*>(out)[i] = o;
}

// ==================================================================
extern "C" void kernel_launch(void* const* d_in, const int* in_sizes, int n_in,
                              void* d_out, int out_size, void* d_ws, size_t ws_size,
                              hipStream_t stream) {
  const int*   inputs = (const int*)d_in[0];
  const int*   Aadj   = (const int*)d_in[1];
  const float* emb    = (const float*)d_in[3];
  const float* rembw  = (const float*)d_in[4];
  const float* transM = (const float*)d_in[5];
  const float* a0     = (const float*)d_in[6];
  const float* a1     = (const float*)d_in[7];
  const float* a2     = (const float*)d_in[8];
  const float* a3     = (const float*)d_in[9];
  const float* ain    = (const float*)d_in[10];
  const int*   hl     = (const int*)d_in[11];
  const int*   tl     = (const int*)d_in[12];

  // workspace layout (~130 MB of the 256 MiB ws)
  u32*   ego1b    = (u32*)d_ws;                         // N_NODE*64 u32
  u32*   ego2b    = ego1b + (size_t)N_NODE * 64;
  u32*   embb     = ego2b + (size_t)N_NODE * 64;
  u8*    projf8   = (u8*)(embb + (size_t)N_NODE * 64);  // 8*N_NODE*256 B = 82MB
  u16*   Wtb      = (u16*)(projf8 + (size_t)N_REL * N_NODE * 256);
  u64*   pay64    = (u64*)(Wtb + (size_t)N_REL * DIM * DIM);
  int*   rank     = (int*)(pay64 + N_EDGES);
  int*   cnt      = rank + N_EDGES;
  int*   rowptr   = cnt + N_NODE;
  int*   bsum     = rowptr + N_NODE + 64;
  float* rsum8    = (float*)(bsum + 256);
  float* tmpK     = rsum8 + 64;                          // BS*SQ*DIM f32
  u16*   ego1f8   = (u16*)(tmpK + (size_t)BS * SQ * DIM); // N_NODE*64 u16 = 5.12MB

  float* out_hidden = (float*)d_out;
  float* out_node   = out_hidden + (size_t)BS * SQ * DIM;

  // ---- prep + CSR scans ----
  hipMemsetAsync(cnt, 0, N_NODE * sizeof(int), stream);
  prep_kernel<<<CONVB + HISTB + N_REL + 1, 256, 0, stream>>>(
      emb, embb, transM, Wtb, rembw, rsum8, hl, cnt, rank);
  bsum_kernel<<<NB, 256, 0, stream>>>(cnt, bsum);
  scan_bsum_kernel<<<1, 256, 0, stream>>>(bsum);
  scan_final_kernel<<<NB, 256, 0, stream>>>(cnt, bsum, rowptr);
  scatter_kernel<<<N_EDGES / 1024, 256, 0, stream>>>(hl, tl, ain, rowptr, rank, pay64);

  // ---- hop 0 (bf16 out + fp8 side-copy) ----
  spmm_pay0<<<(N_NODE * 64) / 256, 256, 0, stream>>>(embb, pay64, rowptr, ego1b, ego1f8);

  // ---- update_attention projection (fp8 split-half output) ----
  proj_mfma4<<<((N_NODE + 127) / 128) * RSPLIT, 256, 0, stream>>>(ego1b, Wtb, projf8);

  // ---- single-pass score + aggregate + normalize (hop 1) ----
  score_spmm<<<(N_NODE * 64) / 256, 256, 0, stream>>>(projf8, ego1f8, pay64, rowptr,
                                                      rsum8, ego2b);

  // ---- session-local double attention ----
  local_agg4<<<BS * 2, 512, 0, stream>>>(emb, ego1b, ego2b, inputs, Aadj,
                                         a0, a1, a2, a3, out_hidden, out_node, tmpK);
  add_kernel<<<(BS * SQ * DIM / 4) / 256, 256, 0, stream>>>(out_hidden, tmpK);
}

// Round 22
// 206.100 us; speedup vs baseline: 1.0397x; 1.0397x over previous
//
#include <hip/hip_runtime.h>

#define N_NODE  40000
#define DIM     128
#define N_REL   8
#define N_EDGES 640000
#define PER_REL (N_EDGES / N_REL)
#define BS      128
#define SQ      50
#define NB      ((N_NODE + 255) / 256)   // 157 scan blocks
#define RSPLIT  8                         // relation split for proj kernel
#define RPB     (N_REL / RSPLIT)          // relations per block (=1)
#define CONVB   ((N_NODE * 64) / 256)     // 10000 conv blocks
#define HISTB   (N_EDGES / 1024)          // 625 hist blocks (4 edges/thread)

typedef unsigned int        u32;
typedef unsigned short      u16;
typedef unsigned char       u8;
typedef unsigned long long  u64;
typedef short  bf16x8 __attribute__((ext_vector_type(8)));
typedef float  f32x4  __attribute__((ext_vector_type(4)));
typedef float  f32x2  __attribute__((ext_vector_type(2)));
typedef u32    u32x4  __attribute__((ext_vector_type(4)));

#if __has_builtin(__builtin_amdgcn_cvt_pk_f32_fp8)
#define HW_FP8_DEC 1
#endif
#if __has_builtin(__builtin_amdgcn_cvt_pk_fp8_f32)
#define HW_FP8_ENC 1
#endif

__device__ __forceinline__ u16 f2bf(float f) {
  union { float f; u32 i; } c; c.f = f;
  u32 b = c.i;
  b += 0x7FFFu + ((b >> 16) & 1u);   // RNE
  return (u16)(b >> 16);
}
__device__ __forceinline__ float bf2f(u32 u) {
  union { u32 i; float f; } c; c.i = u << 16; return c.f;
}
__device__ __forceinline__ float bflo(u32 w) {
  union { u32 i; float f; } c; c.i = w << 16; return c.f;
}
__device__ __forceinline__ float bfhi(u32 w) {
  union { u32 i; float f; } c; c.i = w & 0xffff0000u; return c.f;
}
__device__ __forceinline__ u32 pk2(float a, float b) {
  return (u32)f2bf(a) | ((u32)f2bf(b) << 16);
}
// tanh via exp + hardware rcp (R11-proven)
__device__ __forceinline__ float tanh_fast(float x) {
  float e = __expf(2.f * x);
  return 1.f - 2.f * __builtin_amdgcn_rcpf(e + 1.f);
}

// ---- fp8 OCP e4m3fn software encode/decode (fallbacks; HW-guarded use) ----
__device__ __forceinline__ u32 f2fp8(float f) {
  union { float f; u32 i; } c; c.f = f;
  u32 b = c.i;
  u32 s = (b >> 24) & 0x80u;
  u32 mag = b & 0x7fffffffu;
  mag += 0x7FFFFu + ((mag >> 20) & 1u);      // RNE at bit 20
  int e8 = (int)(mag >> 23) - 120;
  if (e8 >= 16) return s | 0x7Eu;            // clamp to 448
  if (e8 <= 0) {                             // subnormal
    float af = fabsf(f) * 512.f + 0.5f;
    int m2 = (int)af;
    if (m2 > 7) return s | 0x08u;
    return s | (u32)m2;
  }
  return s | ((u32)e8 << 3) | ((mag >> 20) & 7u);
}
__device__ __forceinline__ float fp8d(u32 byte) {
  u32 em = byte & 0x7fu;
  u32 e  = em >> 3;
  u32 M  = e ? (em & 7u) + 8u : em;
  u32 E  = e ? e : 1u;
  union { u32 i; float f; } sc; sc.i = (E + 117u) << 23;   // 2^(E-10)
  float v = (float)M * sc.f;
  return (byte & 0x80u) ? -v : v;
}
__device__ __forceinline__ float fp8dot4(u32 ta, u32 ha) {
#ifdef HW_FP8_DEC
  f32x2 t0 = __builtin_amdgcn_cvt_pk_f32_fp8(ta, 0);
  f32x2 t1 = __builtin_amdgcn_cvt_pk_f32_fp8(ta, 1);
  f32x2 h0 = __builtin_amdgcn_cvt_pk_f32_fp8(ha, 0);
  f32x2 h1 = __builtin_amdgcn_cvt_pk_f32_fp8(ha, 1);
  return t0.x * h0.x + t0.y * h0.y + t1.x * h1.x + t1.y * h1.y;
#else
  return fp8d(ta & 255u) * fp8d(ha & 255u)
       + fp8d((ta >> 8) & 255u) * fp8d((ha >> 8) & 255u)
       + fp8d((ta >> 16) & 255u) * fp8d((ha >> 16) & 255u)
       + fp8d(ta >> 24) * fp8d(ha >> 24);
#endif
}
// decode 2 fp8 packed in low 16 bits of w
__device__ __forceinline__ f32x2 fp8pair(u32 w) {
#ifdef HW_FP8_DEC
  return __builtin_amdgcn_cvt_pk_f32_fp8(w, 0);
#else
  f32x2 r; r.x = fp8d(w & 255u); r.y = fp8d((w >> 8) & 255u); return r;
#endif
}
// encode 2 floats -> 2 fp8 bytes (low u16)
__device__ __forceinline__ u16 fp8enc2(float a, float b) {
#ifdef HW_FP8_ENC
  u32 pk = (u32)__builtin_amdgcn_cvt_pk_fp8_f32(a, b, 0, 0);
  return (u16)(pk & 0xffffu);
#else
  return (u16)(f2fp8(a) | (f2fp8(b) << 8));
#endif
}

// ==================================================================
// fused prep: conv_fp8 | hist+rank | wtrans | rsum8
// conv now encodes the embedding straight to fp8 (only spmm_pay0 reads it)
// ==================================================================
__global__ void __launch_bounds__(256)
prep_kernel(const float* __restrict__ emb, u16* __restrict__ embf8,
            const float* __restrict__ W, u16* __restrict__ Wtb,
            const float* __restrict__ rembw, float* __restrict__ rsum8,
            const int* __restrict__ hl, int* __restrict__ cnt,
            int* __restrict__ rank) {
  int bid = blockIdx.x;
  if (bid < CONVB) {
    int i = bid * 256 + threadIdx.x;
    float2 v = reinterpret_cast<const float2*>(emb)[i];
    embf8[i] = fp8enc2(v.x, v.y);
  } else if (bid < CONVB + HISTB) {
    int base = (bid - CONVB) * 1024 + threadIdx.x;
    int hn[4], rk[4];
    #pragma unroll
    for (int j = 0; j < 4; j++) hn[j] = hl[base + j * 256];
    #pragma unroll
    for (int j = 0; j < 4; j++) rk[j] = atomicAdd(&cnt[hn[j]], 1);
    #pragma unroll
    for (int j = 0; j < 4; j++) rank[base + j * 256] = rk[j];
  } else if (bid < CONVB + HISTB + N_REL) {
    int r = bid - CONVB - HISTB;
    const float* Wr = W + (size_t)r * DIM * DIM;
    u16* o = Wtb + (size_t)r * DIM * DIM;
    for (int x = threadIdx.x; x < DIM * DIM; x += 256) {
      int n = x >> 7, k = x & 127;
      o[x] = f2bf(Wr[k * DIM + n]);
    }
  } else {
    int wv = threadIdx.x >> 6, lane = threadIdx.x & 63;
    for (int r = wv; r < N_REL; r += 4) {
      float s = rembw[r * DIM + lane] + rembw[r * DIM + 64 + lane];
      #pragma unroll
      for (int o = 32; o; o >>= 1) s += __shfl_xor(s, o, 64);
      if (lane == 0) rsum8[r] = s;
    }
  }
}

// ==================================================================
// CSR scans (R17-proven)
// ==================================================================
__global__ void bsum_kernel(const int* __restrict__ cnt, int* __restrict__ bsum) {
  __shared__ int sd[256];
  int i = blockIdx.x * 256 + threadIdx.x;
  sd[threadIdx.x] = (i < N_NODE) ? cnt[i] : 0;
  __syncthreads();
  for (int o = 128; o; o >>= 1) {
    if (threadIdx.x < o) sd[threadIdx.x] += sd[threadIdx.x + o];
    __syncthreads();
  }
  if (!threadIdx.x) bsum[blockIdx.x] = sd[0];
}

__global__ void scan_bsum_kernel(int* __restrict__ bsum) {
  __shared__ int sd[256];
  int t = threadIdx.x;
  int orig = (t < NB) ? bsum[t] : 0;
  sd[t] = orig;
  __syncthreads();
  for (int o = 1; o < 256; o <<= 1) {
    int v = (t >= o) ? sd[t - o] : 0;
    __syncthreads();
    sd[t] += v;
    __syncthreads();
  }
  if (t < NB) bsum[t] = sd[t] - orig;
}

__global__ void scan_final_kernel(const int* __restrict__ cnt, const int* __restrict__ bsum,
                                  int* __restrict__ rowptr) {
  __shared__ int sd[256];
  int t = threadIdx.x;
  int i = blockIdx.x * 256 + t;
  int orig = (i < N_NODE) ? cnt[i] : 0;
  sd[t] = orig;
  __syncthreads();
  for (int o = 1; o < 256; o <<= 1) {
    int v = (t >= o) ? sd[t - o] : 0;
    __syncthreads();
    sd[t] += v;
    __syncthreads();
  }
  int ex = sd[t] - orig + bsum[blockIdx.x];
  if (i < N_NODE) {
    rowptr[i] = ex;
    if (i == N_NODE - 1) rowptr[N_NODE] = ex + orig;
  }
}

// scatter: atomic-free (R17-proven)
__global__ void __launch_bounds__(256)
scatter_kernel(const int* __restrict__ hl, const int* __restrict__ tl,
               const float* __restrict__ ain, const int* __restrict__ rowptr,
               const int* __restrict__ rank, u64* __restrict__ pay64) {
  int base = blockIdx.x * 1024 + threadIdx.x;
  int pos[4];
  u64 pl[4];
  #pragma unroll
  for (int j = 0; j < 4; j++) {
    int e = base + j * 256;
    int hn = hl[e];
    pos[j] = rowptr[hn] + rank[e];
    int r = e / PER_REL;
    u32 lo = (u32)tl[e] | ((u32)hn << 16);
    u32 hi = (u32)r | ((u32)f2bf(ain[e]) << 16);
    pl[j] = ((u64)hi << 32) | lo;
  }
  #pragma unroll
  for (int j = 0; j < 4; j++) pay64[pos[j]] = pl[j];
}

// ==================================================================
// hop0 spmm: fp8 emb gather (128 B/edge) + bf16/fp8 dual output
// ==================================================================
__global__ void __launch_bounds__(256)
spmm_pay0(const u16* __restrict__ xf8, const u64* __restrict__ pay64,
          const int* __restrict__ rowptr, u32* __restrict__ outb,
          u16* __restrict__ outf8) {
  int row = (blockIdx.x * 256 + threadIdx.x) >> 6;
  if (row >= N_NODE) return;
  int lane = threadIdx.x & 63;
  int lo = rowptr[row], n = rowptr[row + 1] - lo;
  float ax = 0.f, ay = 0.f;
  const u16* xl = xf8 + lane;
  int p = 0;
  for (; p + 7 < n; p += 8) {
    u64 q[8]; u32 w[8];
    #pragma unroll
    for (int j = 0; j < 8; j++) q[j] = pay64[lo + p + j];
    #pragma unroll
    for (int j = 0; j < 8; j++) w[j] = xl[(size_t)((u32)q[j] & 0xffffu) << 6];
    #pragma unroll
    for (int j = 0; j < 8; j++) {
      float v = bf2f((u32)(q[j] >> 48));
      f32x2 xv = fp8pair(w[j]);
      ax += v * xv.x;
      ay += v * xv.y;
    }
  }
  for (; p < n; p++) {
    u64 q0 = pay64[lo + p];
    float v0 = bf2f((u32)(q0 >> 48));
    u32 w0 = xl[(size_t)((u32)q0 & 0xffffu) << 6];
    f32x2 xv = fp8pair(w0);
    ax += v0 * xv.x;
    ay += v0 * xv.y;
  }
  outb[((size_t)row << 6) + lane] = pk2(ax, ay);
  outf8[((size_t)row << 6) + lane] = fp8enc2(ax, ay);
}

// ==================================================================
// SINGLE-PASS score + aggregate + rowsum + normalize (R21-proven)
// ==================================================================
__global__ void __launch_bounds__(256)
score_spmm(const u8* __restrict__ projf8, const u16* __restrict__ xf8,
           const u64* __restrict__ pay64, const int* __restrict__ rowptr,
           const float* __restrict__ rsum8, u32* __restrict__ outb) {
  int row = (blockIdx.x * 256 + threadIdx.x) >> 6;
  if (row >= N_NODE) return;
  int lane = threadIdx.x & 63;
  int g8 = lane >> 3, le8 = lane & 7;
  int lo = rowptr[row], n = rowptr[row + 1] - lo;
  const u8* xf8b = reinterpret_cast<const u8*>(xf8);

  float acc[16];
  #pragma unroll
  for (int i = 0; i < 16; i++) acc[i] = 0.f;
  float gsum = 0.f;

  for (int p0 = 0; p0 < n; p0 += 8) {
    int p = p0 + g8;
    bool valid = p < n;
    int r = 0;
    u32x4 xv = (u32x4){0u, 0u, 0u, 0u};
    float s = 0.f;
    if (valid) {
      u64 q = pay64[lo + p];
      int t = (int)((u32)q & 0xffffu);
      r = (int)((u32)(q >> 32) & 0xffu);
      const u8* base = projf8 + (size_t)r * N_NODE * 256;
      u32x4 tv = *reinterpret_cast<const u32x4*>(base + (size_t)t * 256 + le8 * 16);
      u32x4 hv = *reinterpret_cast<const u32x4*>(base + (size_t)row * 256 + 128 + le8 * 16);
      xv = *reinterpret_cast<const u32x4*>(xf8b + (size_t)t * 128 + le8 * 16);
      s = fp8dot4(tv[0], hv[0]) + fp8dot4(tv[1], hv[1])
        + fp8dot4(tv[2], hv[2]) + fp8dot4(tv[3], hv[3]);
    }
    #pragma unroll
    for (int o = 4; o; o >>= 1) s += __shfl_xor(s, o, 64);
    if (valid) {
      float e = __expf(s + rsum8[r]);
      if (le8 == 0) gsum += e;
      #pragma unroll
      for (int c = 0; c < 4; c++) {
        f32x2 loP = fp8pair(xv[c]);
        f32x2 hiP = fp8pair(xv[c] >> 16);
        acc[c * 4 + 0] += e * loP.x;
        acc[c * 4 + 1] += e * loP.y;
        acc[c * 4 + 2] += e * hiP.x;
        acc[c * 4 + 3] += e * hiP.y;
      }
    }
  }

  float rs = gsum;
  #pragma unroll
  for (int o = 32; o; o >>= 1) rs += __shfl_xor(rs, o, 64);
  float inv = (rs > 0.f) ? 1.f / rs : 0.f;

  #pragma unroll
  for (int i = 0; i < 16; i++) {
    #pragma unroll
    for (int o = 8; o < 64; o <<= 1) acc[i] += __shfl_xor(acc[i], o, 64);
  }

  if (g8 == 0) {
    u32 slot[8];
    #pragma unroll
    for (int j = 0; j < 8; j++) slot[j] = pk2(acc[2 * j] * inv, acc[2 * j + 1] * inv);
    u32* dst = outb + ((size_t)row << 6) + le8 * 8;
    *reinterpret_cast<u32x4*>(dst)     = (u32x4){slot[0], slot[1], slot[2], slot[3]};
    *reinterpret_cast<u32x4*>(dst + 4) = (u32x4){slot[4], slot[5], slot[6], slot[7]};
  }
}

// ==================================================================
// projection: A regs, B LDS, fp8 split-half epilogue (R18-proven)
// ==================================================================
__global__ void __launch_bounds__(256)
proj_mfma4(const u32* __restrict__ egob, const u16* __restrict__ Wtb,
           u8* __restrict__ projf8) {
  __shared__ u16 Buf[128 * 136];
  int tid = threadIdx.x;
  int rel0  = (blockIdx.x & (RSPLIT - 1)) * RPB;
  int gbase = (blockIdx.x / RSPLIT) * 128;

  for (int x = tid; x < 128 * 64; x += 256) {
    int m = x >> 6, d2 = x & 63;
    int gm = gbase + m; if (gm >= N_NODE) gm = N_NODE - 1;
    u32 v = egob[((size_t)gm << 6) + d2];
    int byte = (m * 256 + d2 * 4) ^ ((m & 7) << 4);
    *reinterpret_cast<u32*>(reinterpret_cast<char*>(Buf) + byte) = v;
  }
  __syncthreads();

  int w = tid >> 6, lane = tid & 63;
  int l15 = lane & 15, g = lane >> 4;

  bf16x8 afr[2][4];
  #pragma unroll
  for (int kk = 0; kk < 4; kk++) {
    int kb = (kk * 32 + g * 8) * 2;
    #pragma unroll
    for (int mt = 0; mt < 2; mt++) {
      int m = w * 32 + mt * 16 + l15;
      int byte = (m * 256 + kb) ^ ((m & 7) << 4);
      afr[mt][kk] = *reinterpret_cast<bf16x8*>(reinterpret_cast<char*>(Buf) + byte);
    }
  }
  __syncthreads();

  for (int rr = 0; rr < RPB; rr++) {
    int r = rel0 + rr;
    const u32* Wr32 = reinterpret_cast<const u32*>(Wtb + (size_t)r * DIM * DIM);
    for (int x = tid; x < 128 * 64; x += 256) {
      int n = x >> 6, k2 = x & 63;
      int byte = (n * 256 + k2 * 4) ^ ((n & 7) << 4);
      *reinterpret_cast<u32*>(reinterpret_cast<char*>(Buf) + byte) = Wr32[x];
    }
    __syncthreads();

    f32x4 acc[2][8];
    #pragma unroll
    for (int mt = 0; mt < 2; mt++)
      #pragma unroll
      for (int nt = 0; nt < 8; nt++) acc[mt][nt] = (f32x4){0.f, 0.f, 0.f, 0.f};

    #pragma unroll
    for (int kk = 0; kk < 4; kk++) {
      int kb = (kk * 32 + g * 8) * 2;
      #pragma unroll
      for (int nt = 0; nt < 8; nt++) {
        int n = nt * 16 + l15;
        int byte = (n * 256 + kb) ^ ((n & 7) << 4);
        bf16x8 b = *reinterpret_cast<bf16x8*>(reinterpret_cast<char*>(Buf) + byte);
        acc[0][nt] = __builtin_amdgcn_mfma_f32_16x16x32_bf16(afr[0][kk], b, acc[0][nt], 0, 0, 0);
        acc[1][nt] = __builtin_amdgcn_mfma_f32_16x16x32_bf16(afr[1][kk], b, acc[1][nt], 0, 0, 0);
      }
    }
    __syncthreads();

    char* BufB = reinterpret_cast<char*>(Buf);
    #pragma unroll
    for (int mt = 0; mt < 2; mt++)
      #pragma unroll
      for (int reg = 0; reg < 4; reg++) {
        int row = w * 32 + mt * 16 + g * 4 + reg;
        char* rb = BufB + row * 272;
        #pragma unroll
        for (int nt = 0; nt < 8; nt++) {
          float v = acc[mt][nt][reg];
          int col = nt * 16 + l15;
#ifdef HW_FP8_ENC
          u32 pk = (u32)__builtin_amdgcn_cvt_pk_fp8_f32(tanh_fast(v), v, 0, 0);
          rb[col]       = (char)(pk & 255u);
          rb[128 + col] = (char)((pk >> 8) & 255u);
#else
          rb[col]       = (char)f2fp8(tanh_fast(v));
          rb[128 + col] = (char)f2fp8(v);
#endif
        }
      }
    __syncthreads();

    const u32x4* Cs = reinterpret_cast<const u32x4*>(Buf);
    u32* dst = reinterpret_cast<u32*>(projf8 + (size_t)r * N_NODE * 256);
    for (int x = tid; x < 128 * 16; x += 256) {
      int row = x >> 4, q = x & 15;
      int node = gbase + row;
      if (node < N_NODE) {
        u32x4 v = Cs[row * 17 + q];
        *reinterpret_cast<u32x4*>(dst + ((size_t)node << 6) + q * 4) = v;
      }
    }
    __syncthreads();
  }
}

// ==================================================================
// local_agg via MFMA (R5-proven, unchanged)
// ==================================================================
__global__ void __launch_bounds__(512)
local_agg4(const float* __restrict__ emb, const u32* __restrict__ ego1b,
           const u32* __restrict__ ego2b, const int* __restrict__ inp,
           const int* __restrict__ Aadj,
           const float* __restrict__ a0, const float* __restrict__ a1,
           const float* __restrict__ a2, const float* __restrict__ a3,
           float* __restrict__ out_hidden, float* __restrict__ out_node,
           float* __restrict__ tmpK) {
  __shared__ u16   Qb[64 * 256];
  __shared__ u16   hTb[128 * 64];
  __shared__ float aC[4][256];
  __shared__ float S[4][64 * 66];
  __shared__ u16   P[64 * 64];
  __shared__ float sinv[64];
  __shared__ int   adjL[SQ * SQ];

  int b = blockIdx.x >> 1, which = blockIdx.x & 1;
  int tid = threadIdx.x;

  {
    int k = tid >> 7, d = tid & 127;
    const float* ap = (k == 0) ? a0 : (k == 1) ? a1 : (k == 2) ? a2 : a3;
    float av = ap[d];
    aC[k][d] = 0.6f * av;
    aC[k][128 + d] = 0.4f * av;
  }
  for (int x = tid; x < SQ * SQ; x += 512) adjL[x] = Aadj[b * SQ * SQ + x];
  for (int x = tid; x < 128 * 16; x += 512) {
    int d = x >> 4, j = 48 + (x & 15);
    if (j >= 50) {
      int byte = (d * 128 + j * 2) ^ ((d & 7) << 4);
      *reinterpret_cast<u16*>(reinterpret_cast<char*>(hTb) + byte) = 0;
    }
  }
  for (int x = tid; x < SQ * 64; x += 512) {
    int j = x >> 6, d2 = (x & 63) << 1;
    int node = inp[b * SQ + j];
    float v0, v1;
    if (which == 0) {
      float2 vv = *reinterpret_cast<const float2*>(emb + (size_t)node * DIM + d2);
      v0 = vv.x; v1 = vv.y;
      *reinterpret_cast<float2*>(out_node + (size_t)(b * SQ + j) * DIM + d2) = vv;
    } else {
      u32 w1 = ego1b[((size_t)node << 6) + (d2 >> 1)];
      u32 w2 = ego2b[((size_t)node << 6) + (d2 >> 1)];
      v0 = 0.5f * (bf2f(w1 & 0xffffu) + bf2f(w2 & 0xffffu));
      v1 = 0.5f * (bf2f(w1 >> 16) + bf2f(w2 >> 16));
    }
    u16 b0 = f2bf(v0), b1 = f2bf(v1);
    { int byte = (j * 512 + d2 * 2) ^ ((j & 7) << 4);
      *reinterpret_cast<u32*>(reinterpret_cast<char*>(Qb) + byte) = (u32)b0 | ((u32)b1 << 16); }
    { int byte = (j * 512 + 256 + d2 * 2) ^ ((j & 7) << 4);
      u32 m0 = b0 & 0x7fffu, m1 = b1 & 0x7fffu;
      *reinterpret_cast<u32*>(reinterpret_cast<char*>(Qb) + byte) = m0 | (m1 << 16); }
    { int byte = (d2 * 128 + j * 2) ^ ((d2 & 7) << 4);
      *reinterpret_cast<u16*>(reinterpret_cast<char*>(hTb) + byte) = b0; }
    { int byte = ((d2 + 1) * 128 + j * 2) ^ (((d2 + 1) & 7) << 4);
      *reinterpret_cast<u16*>(reinterpret_cast<char*>(hTb) + byte) = b1; }
  }
  __syncthreads();

  int w = tid >> 6, lane = tid & 63;
  int l15 = lane & 15, g = lane >> 4;

  {
    int k = w >> 1, half = w & 1;
    const float* aCk = aC[k];
    f32x4 acc[2][4];
    #pragma unroll
    for (int mt = 0; mt < 2; mt++)
      #pragma unroll
      for (int nt = 0; nt < 4; nt++) acc[mt][nt] = (f32x4){0.f, 0.f, 0.f, 0.f};
    for (int ks = 0; ks < 8; ks++) {
      int kb = ks * 32 + g * 8;
      float4 c01 = *reinterpret_cast<const float4*>(aCk + kb);
      float4 c23 = *reinterpret_cast<const float4*>(aCk + kb + 4);
      bf16x8 afr[2];
      #pragma unroll
      for (int mt = 0; mt < 2; mt++) {
        int m = (half * 2 + mt) * 16 + l15;
        int byte = (m * 512 + kb * 2) ^ ((m & 7) << 4);
        union { bf16x8 v; u32 u[4]; } qv, o;
        qv.v = *reinterpret_cast<bf16x8*>(reinterpret_cast<char*>(Qb) + byte);
        o.u[0] = pk2(bf2f(qv.u[0] & 0xffffu) * c01.x, bf2f(qv.u[0] >> 16) * c01.y);
        o.u[1] = pk2(bf2f(qv.u[1] & 0xffffu) * c01.z, bf2f(qv.u[1] >> 16) * c01.w);
        o.u[2] = pk2(bf2f(qv.u[2] & 0xffffu) * c23.x, bf2f(qv.u[2] >> 16) * c23.y);
        o.u[3] = pk2(bf2f(qv.u[3] & 0xffffu) * c23.z, bf2f(qv.u[3] >> 16) * c23.w);
        afr[mt] = o.v;
      }
      #pragma unroll
      for (int nt = 0; nt < 4; nt++) {
        int n = nt * 16 + l15;
        int byte = (n * 512 + kb * 2) ^ ((n & 7) << 4);
        bf16x8 bfr = *reinterpret_cast<bf16x8*>(reinterpret_cast<char*>(Qb) + byte);
        acc[0][nt] = __builtin_amdgcn_mfma_f32_16x16x32_bf16(afr[0], bfr, acc[0][nt], 0, 0, 0);
        acc[1][nt] = __builtin_amdgcn_mfma_f32_16x16x32_bf16(afr[1], bfr, acc[1][nt], 0, 0, 0);
      }
    }
    #pragma unroll
    for (int mt = 0; mt < 2; mt++)
      #pragma unroll
      for (int nt = 0; nt < 4; nt++)
        #pragma unroll
        for (int reg = 0; reg < 4; reg++) {
          int m = (half * 2 + mt) * 16 + g * 4 + reg;
          int n = nt * 16 + l15;
          S[k][m * 66 + n] = acc[mt][nt][reg];
        }
  }
  __syncthreads();

  for (int i = w; i < SQ; i += 8) {
    float p = 0.f;
    if (lane < SQ) {
      int sel = adjL[i * SQ + lane];
      if (sel > 0) p = __expf(S[sel - 1][i * 66 + lane]);
    }
    float s = p;
    #pragma unroll
    for (int off = 32; off; off >>= 1) s += __shfl_xor(s, off, 64);
    if (lane == 0) sinv[i] = (s > 0.f) ? 1.f / s : 0.f;
    int byte = (i * 128 + lane * 2) ^ ((i & 7) << 4);
    *reinterpret_cast<u16*>(reinterpret_cast<char*>(P) + byte) = f2bf(p);
  }
  __syncthreads();

  {
    int mt = w >> 1, ng = w & 1;
    f32x4 acc[4];
    #pragma unroll
    for (int nt = 0; nt < 4; nt++) acc[nt] = (f32x4){0.f, 0.f, 0.f, 0.f};
    #pragma unroll
    for (int ks = 0; ks < 2; ks++) {
      int kb = ks * 32 + g * 8;
      int m = mt * 16 + l15;
      int abyte = (m * 128 + kb * 2) ^ ((m & 7) << 4);
      bf16x8 afr = *reinterpret_cast<bf16x8*>(reinterpret_cast<char*>(P) + abyte);
      #pragma unroll
      for (int nt = 0; nt < 4; nt++) {
        int d = (ng * 4 + nt) * 16 + l15;
        int byte = (d * 128 + kb * 2) ^ ((d & 7) << 4);
        bf16x8 bfr = *reinterpret_cast<bf16x8*>(reinterpret_cast<char*>(hTb) + byte);
        acc[nt] = __builtin_amdgcn_mfma_f32_16x16x32_bf16(afr, bfr, acc[nt], 0, 0, 0);
      }
    }
    float* dst = which ? tmpK : out_hidden;
    #pragma unroll
    for (int nt = 0; nt < 4; nt++)
      #pragma unroll
      for (int reg = 0; reg < 4; reg++) {
        int i = mt * 16 + g * 4 + reg;
        if (i < SQ) {
          int d = (ng * 4 + nt) * 16 + l15;
          dst[(size_t)(b * SQ + i) * DIM + d] = acc[nt][reg] * sinv[i];
        }
      }
  }
}

__global__ void add_kernel(float* __restrict__ out, const float* __restrict__ add) {
  int i = blockIdx.x * 256 + threadIdx.x;
  float4 a = reinterpret_cast<const float4*>(add)[i];
  float4 o = reinterpret_cast<float4*>(out)[i];
  o.x += a.x; o.y += a.y; o.z += a.z; o.w += a.w;
  reinterpret_cast<float4*>(out)[i] = o;
}

// ==================================================================
extern "C" void kernel_launch(void* const* d_in, const int* in_sizes, int n_in,
                              void* d_out, int out_size, void* d_ws, size_t ws_size,
                              hipStream_t stream) {
  const int*   inputs = (const int*)d_in[0];
  const int*   Aadj   = (const int*)d_in[1];
  const float* emb    = (const float*)d_in[3];
  const float* rembw  = (const float*)d_in[4];
  const float* transM = (const float*)d_in[5];
  const float* a0     = (const float*)d_in[6];
  const float* a1     = (const float*)d_in[7];
  const float* a2     = (const float*)d_in[8];
  const float* a3     = (const float*)d_in[9];
  const float* ain    = (const float*)d_in[10];
  const int*   hl     = (const int*)d_in[11];
  const int*   tl     = (const int*)d_in[12];

  // workspace layout (~125 MB of the 256 MiB ws)
  u32*   ego1b    = (u32*)d_ws;                         // N_NODE*64 u32
  u32*   ego2b    = ego1b + (size_t)N_NODE * 64;
  u16*   embf8    = (u16*)(ego2b + (size_t)N_NODE * 64); // N_NODE*64 u16 = 5.12MB
  u8*    projf8   = (u8*)(embf8 + (size_t)N_NODE * 64);  // 8*N_NODE*256 B = 82MB
  u16*   Wtb      = (u16*)(projf8 + (size_t)N_REL * N_NODE * 256);
  u64*   pay64    = (u64*)(Wtb + (size_t)N_REL * DIM * DIM);
  int*   rank     = (int*)(pay64 + N_EDGES);
  int*   cnt      = rank + N_EDGES;
  int*   rowptr   = cnt + N_NODE;
  int*   bsum     = rowptr + N_NODE + 64;
  float* rsum8    = (float*)(bsum + 256);
  float* tmpK     = rsum8 + 64;                          // BS*SQ*DIM f32
  u16*   ego1f8   = (u16*)(tmpK + (size_t)BS * SQ * DIM); // N_NODE*64 u16 = 5.12MB

  float* out_hidden = (float*)d_out;
  float* out_node   = out_hidden + (size_t)BS * SQ * DIM;

  // ---- prep + CSR scans ----
  hipMemsetAsync(cnt, 0, N_NODE * sizeof(int), stream);
  prep_kernel<<<CONVB + HISTB + N_REL + 1, 256, 0, stream>>>(
      emb, embf8, transM, Wtb, rembw, rsum8, hl, cnt, rank);
  bsum_kernel<<<NB, 256, 0, stream>>>(cnt, bsum);
  scan_bsum_kernel<<<1, 256, 0, stream>>>(bsum);
  scan_final_kernel<<<NB, 256, 0, stream>>>(cnt, bsum, rowptr);
  scatter_kernel<<<N_EDGES / 1024, 256, 0, stream>>>(hl, tl, ain, rowptr, rank, pay64);

  // ---- hop 0 (fp8 emb gather -> bf16 + fp8 outputs) ----
  spmm_pay0<<<(N_NODE * 64) / 256, 256, 0, stream>>>(embf8, pay64, rowptr, ego1b, ego1f8);

  // ---- update_attention projection (fp8 split-half output) ----
  proj_mfma4<<<((N_NODE + 127) / 128) * RSPLIT, 256, 0, stream>>>(ego1b, Wtb, projf8);

  // ---- single-pass score + aggregate + normalize (hop 1) ----
  score_spmm<<<(N_NODE * 64) / 256, 256, 0, stream>>>(projf8, ego1f8, pay64, rowptr,
                                                      rsum8, ego2b);

  // ---- session-local double attention ----
  local_agg4<<<BS * 2, 512, 0, stream>>>(emb, ego1b, ego2b, inputs, Aadj,
                                         a0, a1, a2, a3, out_hidden, out_node, tmpK);
  add_kernel<<<(BS * SQ * DIM / 4) / 256, 256, 0, stream>>>(out_hidden, tmpK);
}